// Round 9
// baseline (648.371 us; speedup 1.0000x reference)
//
#include <hip/hip_runtime.h>

#define H 128
#define H2 256
#define NODE_IN 32
#define BN_EPS 1e-5f

typedef __bf16 bf16x8 __attribute__((ext_vector_type(8)));
typedef __bf16 bf16x4 __attribute__((ext_vector_type(4)));
typedef float f32x4 __attribute__((ext_vector_type(4)));

#define MFMA(a, b, c) __builtin_amdgcn_mfma_f32_16x16x32_bf16(a, b, c, 0, 0, 0)

// ---------------------------------------------------------------------------
// Weights -> bf16, transposed, XOR-swizzled GLOBAL layout (consumed linearly
// by global_load_lds so the LDS copy is swizzled; reads use chunk^(row&7)).
// W1 [L][128][256] -> per layer at l*131072       : row n(0..255) x 256B
// W2 [L][256][128] -> per layer at l*131072+65536 : row n(0..127) x 512B
// embW [32][128]   -> at L*131072: Wt_e[c][k], row c(0..127) x 64B (no swizzle)
__global__ __launch_bounds__(256) void convert_weights_kernel(
    const float* __restrict__ W1, const float* __restrict__ W2,
    const float* __restrict__ embW, char* __restrict__ Ws, int L)
{
    int idx = blockIdx.x * 256 + threadIdx.x;
    int per = H * H2;
    int total = L * per;
    if (idx < total) {
        int l = idx / per, r = idx % per;
        int k = r / H2, n = r % H2;          // W1[l][k][n]
        int c = k >> 3, e = k & 7;
        size_t off = (size_t)l * 131072 + n * 256 + (((c ^ (n & 7)) << 4)) + e * 2;
        *(__bf16*)(Ws + off) = (__bf16)W1[idx];
    } else if (idx < 2 * total) {
        int j = idx - total;
        int l = j / per, r = j % per;
        int k = r / H, n = r % H;            // W2[l][k][n]
        int c = k >> 3, e = k & 7;
        size_t off = (size_t)l * 131072 + 65536 + n * 512 + (((c ^ (n & 7)) << 4)) + e * 2;
        *(__bf16*)(Ws + off) = (__bf16)W2[j];
    } else if (idx < 2 * total + H * NODE_IN) {
        int j = idx - 2 * total;
        int k = j / H, c = j % H;            // embW[k][c]
        size_t off = (size_t)L * 131072 + c * 64 + k * 2;
        *(__bf16*)(Ws + off) = (__bf16)embW[j];
    }
}

// ---------------------------------------------------------------------------
// h0 = x @ emb_W + emb_b via MFMA (K=32 = one mfma_16x16x32).
// 8 waves x 16 rows; A = Wt_e frags (regs, from L2), B = x rows (fp32->bf16).
__global__ __launch_bounds__(512) void embed_kernel(
    const float* __restrict__ x, const char* __restrict__ Wse,
    const float* __restrict__ bias, __bf16* __restrict__ h, int N)
{
    int tid = threadIdx.x;
    int w = tid >> 6, lane = tid & 63;
    int l15 = lane & 15, kg = lane >> 4;

    bf16x8 aw[8];
#pragma unroll
    for (int nt = 0; nt < 8; ++nt)
        aw[nt] = *(const bf16x8*)(Wse + (nt * 16 + l15) * 64 + kg * 16);

    int r = (blockIdx.x * 8 + w) * 16 + l15;
    bool ok = (r < N);

    bf16x8 xb = {};
    if (ok) {
        float4 v0 = *(const float4*)&x[(size_t)r * NODE_IN + kg * 8];
        float4 v1 = *(const float4*)&x[(size_t)r * NODE_IN + kg * 8 + 4];
        xb[0] = (__bf16)v0.x; xb[1] = (__bf16)v0.y;
        xb[2] = (__bf16)v0.z; xb[3] = (__bf16)v0.w;
        xb[4] = (__bf16)v1.x; xb[5] = (__bf16)v1.y;
        xb[6] = (__bf16)v1.z; xb[7] = (__bf16)v1.w;
    }

    __bf16* hr = h + (size_t)r * H;
#pragma unroll
    for (int nt = 0; nt < 8; ++nt) {
        f32x4 acc = {0.f, 0.f, 0.f, 0.f};
        acc = MFMA(aw[nt], xb, acc);
        if (ok) {
            float4 bb = *(const float4*)&bias[nt * 16 + kg * 4];
            bf16x4 hv;
            hv[0] = (__bf16)(acc[0] + bb.x);
            hv[1] = (__bf16)(acc[1] + bb.y);
            hv[2] = (__bf16)(acc[2] + bb.z);
            hv[3] = (__bf16)(acc[3] + bb.w);
            *(bf16x4*)(hr + nt * 16 + kg * 4) = hv;
        }
    }
}

// ---------------------------------------------------------------------------
// CSR build
__global__ __launch_bounds__(256) void hist_kernel(
    const int* __restrict__ dst, int* __restrict__ deg, int E)
{
    int e = blockIdx.x * 256 + threadIdx.x;
    if (e < E) atomicAdd(&deg[dst[e]], 1);
}

__global__ __launch_bounds__(256) void scan_partial_kernel(
    const int* __restrict__ deg, int* __restrict__ bsum, int N)
{
    __shared__ int red[256];
    int b = blockIdx.x, t = threadIdx.x;
    int base = b * 2048 + t * 8;
    int s = 0;
#pragma unroll
    for (int i = 0; i < 8; ++i) { int idx = base + i; if (idx < N) s += deg[idx]; }
    red[t] = s;
    __syncthreads();
    for (int d = 128; d > 0; d >>= 1) {
        if (t < d) red[t] += red[t + d];
        __syncthreads();
    }
    if (t == 0) bsum[b] = red[0];
}

__global__ __launch_bounds__(256) void scan_bsum_kernel(
    int* __restrict__ bsum, int* __restrict__ total, int numB)
{
    __shared__ int ts[256];
    int t = threadIdx.x;
    int v = (t < numB) ? bsum[t] : 0;
    ts[t] = v;
    __syncthreads();
    for (int d = 1; d < 256; d <<= 1) {
        int u = (t >= d) ? ts[t - d] : 0;
        __syncthreads();
        ts[t] += u;
        __syncthreads();
    }
    if (t < numB) bsum[t] = ts[t] - v;
    if (t == 255) *total = ts[255];
}

__global__ __launch_bounds__(256) void scan_apply_kernel(
    const int* __restrict__ deg, const int* __restrict__ bsum,
    int* __restrict__ offp, int* __restrict__ cursor, int N)
{
    __shared__ int ts[256];
    int b = blockIdx.x, t = threadIdx.x;
    int base = b * 2048 + t * 8;
    int loc[8];
    int s = 0;
#pragma unroll
    for (int i = 0; i < 8; ++i) {
        int idx = base + i;
        loc[i] = (idx < N) ? deg[idx] : 0;
        s += loc[i];
    }
    ts[t] = s;
    __syncthreads();
    for (int d = 1; d < 256; d <<= 1) {
        int u = (t >= d) ? ts[t - d] : 0;
        __syncthreads();
        ts[t] += u;
        __syncthreads();
    }
    int run = bsum[b] + ts[t] - s;
#pragma unroll
    for (int i = 0; i < 8; ++i) {
        int idx = base + i;
        if (idx < N) { offp[idx] = run; cursor[idx] = run; }
        run += loc[i];
    }
}

__global__ __launch_bounds__(256) void fill_kernel(
    const int* __restrict__ src, const int* __restrict__ dst,
    int* __restrict__ cursor, int* __restrict__ srclist, int E)
{
    int e = blockIdx.x * 256 + threadIdx.x;
    if (e < E) {
        int pos = atomicAdd(&cursor[dst[e]], 1);
        srclist[pos] = src[e];
    }
}

// ---------------------------------------------------------------------------
// zg[v] = bf16( f(hin[v]) + sum_{nbr} f(hin[src]) ); f = BN?relu(v*sc+sh):v
template <int BN>
__global__ __launch_bounds__(256) void gather_kernel(
    const __bf16* __restrict__ hin, const float* __restrict__ ss,
    const int* __restrict__ offp, const int* __restrict__ srclist,
    __bf16* __restrict__ zg, int N)
{
    int gid = blockIdx.x * 256 + threadIdx.x;
    int v = gid >> 4;
    if (v >= N) return;
    int c16 = gid & 15;
    float sc[8], sh[8];
    if (BN) {
#pragma unroll
        for (int j = 0; j < 8; ++j) { sc[j] = ss[c16 * 8 + j]; sh[j] = ss[H + c16 * 8 + j]; }
    }
    float acc[8];
    bf16x8 sv = *(const bf16x8*)(hin + (size_t)v * H + c16 * 8);
#pragma unroll
    for (int j = 0; j < 8; ++j) {
        float f = (float)sv[j];
        acc[j] = BN ? fmaxf(f * sc[j] + sh[j], 0.f) : f;
    }
    int i0 = offp[v], i1 = offp[v + 1];
    int i = i0;
    for (; i + 1 < i1; i += 2) {
        int s0 = srclist[i], s1 = srclist[i + 1];
        bf16x8 u0 = *(const bf16x8*)(hin + (size_t)s0 * H + c16 * 8);
        bf16x8 u1 = *(const bf16x8*)(hin + (size_t)s1 * H + c16 * 8);
#pragma unroll
        for (int j = 0; j < 8; ++j) {
            float f0 = (float)u0[j], f1 = (float)u1[j];
            if (BN) {
                f0 = fmaxf(f0 * sc[j] + sh[j], 0.f);
                f1 = fmaxf(f1 * sc[j] + sh[j], 0.f);
            }
            acc[j] += f0 + f1;
        }
    }
    if (i < i1) {
        int s0 = srclist[i];
        bf16x8 u0 = *(const bf16x8*)(hin + (size_t)s0 * H + c16 * 8);
#pragma unroll
        for (int j = 0; j < 8; ++j) {
            float f0 = (float)u0[j];
            if (BN) f0 = fmaxf(f0 * sc[j] + sh[j], 0.f);
            acc[j] += f0;
        }
    }
    bf16x8 o;
#pragma unroll
    for (int j = 0; j < 8; ++j) o[j] = (__bf16)acc[j];
    *(bf16x8*)(zg + (size_t)v * H + c16 * 8) = o;
}

// ---------------------------------------------------------------------------
// GEMM1: hid = relu(zg @ W1 + b1). 8 waves/block; W1 (64KB, swizzled) in LDS;
// one barrier; each wave TWO independent 16-row tiles (stage amortized 2x).
// Swapped MFMA: A = W1 frag (LDS), B = zg rows. D lane -> node l15, 4 cols.
__global__ __launch_bounds__(512, 2) void gemm1_kernel(
    const __bf16* __restrict__ zg, __bf16* __restrict__ hid,
    const char* __restrict__ Ws1, const float* __restrict__ b1l, int N)
{
    __shared__ __align__(16) char lds[65536];
    int tid = threadIdx.x;
    int w = tid >> 6, lane = tid & 63;
    int l15 = lane & 15, kg = lane >> 4;

#pragma unroll
    for (int i = 0; i < 8; ++i) {
        const char* g = Ws1 + i * 8192 + tid * 16;
        char* l = lds + i * 8192 + w * 1024;   // wave-uniform base; HW adds lane*16
        __builtin_amdgcn_global_load_lds(
            (const __attribute__((address_space(1))) void*)g,
            (__attribute__((address_space(3))) void*)l, 16, 0, 0);
    }

    int tile0 = blockIdx.x * 16 + w * 2;
    int r0 = tile0 * 16 + l15;
    int r1 = r0 + 16;
    bool ok0 = (r0 < N), ok1 = (r1 < N);

    // tile-0 B fragments preloaded (overlaps weight staging)
    bf16x8 zb[4];
    {
        const __bf16* zr = zg + (size_t)r0 * H + kg * 8;
#pragma unroll
        for (int kk = 0; kk < 4; ++kk) {
            bf16x8 v = {};
            if (ok0) v = *(const bf16x8*)(zr + kk * 32);
            zb[kk] = v;
        }
    }

    __syncthreads();   // weights resident

    const int xsw = (l15 & 7) << 4;

    // ---- tile 0 ----
    {
        __bf16* hr = hid + (size_t)r0 * H2;
#pragma unroll
        for (int nt = 0; nt < 16; ++nt) {
            f32x4 acc = {0.f, 0.f, 0.f, 0.f};
            const char* wrow = lds + (nt * 16 + l15) * 256;
#pragma unroll
            for (int kk = 0; kk < 4; ++kk) {
                bf16x8 aw = *(const bf16x8*)(wrow + (((kk * 4 + kg) << 4) ^ xsw));
                acc = MFMA(aw, zb[kk], acc);
            }
            if (ok0) {
                float4 bb = *(const float4*)&b1l[nt * 16 + kg * 4];
                bf16x4 hv;
                hv[0] = (__bf16)fmaxf(acc[0] + bb.x, 0.f);
                hv[1] = (__bf16)fmaxf(acc[1] + bb.y, 0.f);
                hv[2] = (__bf16)fmaxf(acc[2] + bb.z, 0.f);
                hv[3] = (__bf16)fmaxf(acc[3] + bb.w, 0.f);
                *(bf16x4*)(hr + nt * 16 + kg * 4) = hv;
            }
        }
    }

    // ---- tile 1 ----
    {
        const __bf16* zr = zg + (size_t)r1 * H + kg * 8;
#pragma unroll
        for (int kk = 0; kk < 4; ++kk) {
            bf16x8 v = {};
            if (ok1) v = *(const bf16x8*)(zr + kk * 32);
            zb[kk] = v;
        }
        __bf16* hr = hid + (size_t)r1 * H2;
#pragma unroll
        for (int nt = 0; nt < 16; ++nt) {
            f32x4 acc = {0.f, 0.f, 0.f, 0.f};
            const char* wrow = lds + (nt * 16 + l15) * 256;
#pragma unroll
            for (int kk = 0; kk < 4; ++kk) {
                bf16x8 aw = *(const bf16x8*)(wrow + (((kk * 4 + kg) << 4) ^ xsw));
                acc = MFMA(aw, zb[kk], acc);
            }
            if (ok1) {
                float4 bb = *(const float4*)&b1l[nt * 16 + kg * 4];
                bf16x4 hv;
                hv[0] = (__bf16)fmaxf(acc[0] + bb.x, 0.f);
                hv[1] = (__bf16)fmaxf(acc[1] + bb.y, 0.f);
                hv[2] = (__bf16)fmaxf(acc[2] + bb.z, 0.f);
                hv[3] = (__bf16)fmaxf(acc[3] + bb.w, 0.f);
                *(bf16x4*)(hr + nt * 16 + kg * 4) = hv;
            }
        }
    }
}

// ---------------------------------------------------------------------------
// GEMM2: zp = hid @ W2 + b2 (pre-BN) + per-wave BN partial sums -> spart.
// Same structure; W2 (64KB) in LDS; two tiles per wave; stats shfl-reduced.
__global__ __launch_bounds__(512, 2) void gemm2_kernel(
    const __bf16* __restrict__ hid, __bf16* __restrict__ zpb,
    const char* __restrict__ Ws2, const float* __restrict__ b2l,
    float* __restrict__ spart, int N)
{
    __shared__ __align__(16) char lds[65536];
    int tid = threadIdx.x;
    int w = tid >> 6, lane = tid & 63;
    int l15 = lane & 15, kg = lane >> 4;

#pragma unroll
    for (int i = 0; i < 8; ++i) {
        const char* g = Ws2 + i * 8192 + tid * 16;
        char* l = lds + i * 8192 + w * 1024;
        __builtin_amdgcn_global_load_lds(
            (const __attribute__((address_space(1))) void*)g,
            (__attribute__((address_space(3))) void*)l, 16, 0, 0);
    }

    int tile0 = blockIdx.x * 16 + w * 2;
    int r0 = tile0 * 16 + l15;
    int r1 = r0 + 16;
    bool ok0 = (r0 < N), ok1 = (r1 < N);

    bf16x8 bd[8];
    {
        const __bf16* hr = hid + (size_t)r0 * H2 + kg * 8;
#pragma unroll
        for (int kk = 0; kk < 8; ++kk) {
            bf16x8 v = {};
            if (ok0) v = *(const bf16x8*)(hr + kk * 32);
            bd[kk] = v;
        }
    }

    __syncthreads();

    const int xsw = (l15 & 7) << 4;
    float pS[8][4], pQ[8][4];
#pragma unroll
    for (int a = 0; a < 8; ++a)
#pragma unroll
        for (int q = 0; q < 4; ++q) { pS[a][q] = 0.f; pQ[a][q] = 0.f; }

#pragma unroll
    for (int s = 0; s < 2; ++s) {
        if (s == 1) {
            const __bf16* hr = hid + (size_t)r1 * H2 + kg * 8;
#pragma unroll
            for (int kk = 0; kk < 8; ++kk) {
                bf16x8 v = {};
                if (ok1) v = *(const bf16x8*)(hr + kk * 32);
                bd[kk] = v;
            }
        }
        int r = s ? r1 : r0;
        bool ok = s ? ok1 : ok0;
        __bf16* zr = zpb + (size_t)r * H;
#pragma unroll
        for (int nt2 = 0; nt2 < 8; ++nt2) {
            f32x4 acc = {0.f, 0.f, 0.f, 0.f};
            const char* wrow = lds + (nt2 * 16 + l15) * 512;
#pragma unroll
            for (int kk = 0; kk < 8; ++kk) {
                bf16x8 aw = *(const bf16x8*)(wrow + (((kk * 4 + kg) << 4) ^ xsw));
                acc = MFMA(aw, bd[kk], acc);
            }
            if (ok) {
                float4 bb = *(const float4*)&b2l[nt2 * 16 + kg * 4];
                float v0 = acc[0] + bb.x, v1 = acc[1] + bb.y;
                float v2 = acc[2] + bb.z, v3 = acc[3] + bb.w;
                bf16x4 ov;
                ov[0] = (__bf16)v0; ov[1] = (__bf16)v1;
                ov[2] = (__bf16)v2; ov[3] = (__bf16)v3;
                *(bf16x4*)(zr + nt2 * 16 + kg * 4) = ov;
                pS[nt2][0] += v0; pQ[nt2][0] += v0 * v0;
                pS[nt2][1] += v1; pQ[nt2][1] += v1 * v1;
                pS[nt2][2] += v2; pQ[nt2][2] += v2 * v2;
                pS[nt2][3] += v3; pQ[nt2][3] += v3 * v3;
            }
        }
    }

    // reduce over the 16 l15-lanes of each kg group; write per-wave partials
#pragma unroll
    for (int nt2 = 0; nt2 < 8; ++nt2)
#pragma unroll
        for (int q = 0; q < 4; ++q) {
            float s = pS[nt2][q], u = pQ[nt2][q];
            s += __shfl_xor(s, 1, 64); u += __shfl_xor(u, 1, 64);
            s += __shfl_xor(s, 2, 64); u += __shfl_xor(u, 2, 64);
            s += __shfl_xor(s, 4, 64); u += __shfl_xor(u, 4, 64);
            s += __shfl_xor(s, 8, 64); u += __shfl_xor(u, 8, 64);
            pS[nt2][q] = s; pQ[nt2][q] = u;
        }
    if (l15 == 0) {
        size_t row = (size_t)(blockIdx.x * 8 + w) * 256;
#pragma unroll
        for (int nt2 = 0; nt2 < 8; ++nt2) {
            *(float4*)&spart[row + nt2 * 16 + kg * 4] =
                make_float4(pS[nt2][0], pS[nt2][1], pS[nt2][2], pS[nt2][3]);
            *(float4*)&spart[row + 128 + nt2 * 16 + kg * 4] =
                make_float4(pQ[nt2][0], pQ[nt2][1], pQ[nt2][2], pQ[nt2][3]);
        }
    }
}

// ---------------------------------------------------------------------------
__global__ __launch_bounds__(256) void reduce_stats_kernel(
    const float* __restrict__ spart, float* __restrict__ stats, int R)
{
    int t = threadIdx.x;
    int b = blockIdx.x;
    int per = (R + gridDim.x - 1) / gridDim.x;
    int r0 = b * per, r1 = r0 + per;
    if (r1 > R) r1 = R;
    float s = 0.f;
    for (int r = r0; r < r1; ++r) s += spart[(size_t)r * 256 + t];
    atomicAdd(&stats[t], s);
}

// ---------------------------------------------------------------------------
__global__ void bn_finalize_kernel(const float* __restrict__ stats,
                                   const float* __restrict__ gamma,
                                   const float* __restrict__ beta,
                                   float* __restrict__ ss, int N)
{
    int j = threadIdx.x;
    float invN = 1.0f / (float)N;
    float mean = stats[j] * invN;
    float var = stats[H + j] * invN - mean * mean;
    float sc = gamma[j] * rsqrtf(var + BN_EPS);
    ss[j] = sc;
    ss[H + j] = beta[j] - mean * sc;
}

// ---------------------------------------------------------------------------
// out = relu(zpb*scale + shift), bf16 -> fp32
__global__ __launch_bounds__(256) void bn_apply_kernel(
    const __bf16* __restrict__ zpb, const float* __restrict__ ss,
    float* __restrict__ out, int N)
{
    size_t i = (size_t)blockIdx.x * 256 + threadIdx.x;   // 8-elem units
    size_t total = (size_t)N * (H / 8);
    if (i >= total) return;
    int c8 = (int)(i & (H / 8 - 1));
    bf16x8 v = *(const bf16x8*)(zpb + i * 8);
    float4 o0, o1;
    const float* scp = &ss[c8 * 8];
    const float* shp = &ss[H + c8 * 8];
    o0.x = fmaxf((float)v[0] * scp[0] + shp[0], 0.f);
    o0.y = fmaxf((float)v[1] * scp[1] + shp[1], 0.f);
    o0.z = fmaxf((float)v[2] * scp[2] + shp[2], 0.f);
    o0.w = fmaxf((float)v[3] * scp[3] + shp[3], 0.f);
    o1.x = fmaxf((float)v[4] * scp[4] + shp[4], 0.f);
    o1.y = fmaxf((float)v[5] * scp[5] + shp[5], 0.f);
    o1.z = fmaxf((float)v[6] * scp[6] + shp[6], 0.f);
    o1.w = fmaxf((float)v[7] * scp[7] + shp[7], 0.f);
    ((float4*)out)[i * 2] = o0;
    ((float4*)out)[i * 2 + 1] = o1;
}

// ---------------------------------------------------------------------------
static inline char* align_up(char* p, size_t a) {
    return (char*)(((uintptr_t)p + a - 1) & ~(uintptr_t)(a - 1));
}

extern "C" void kernel_launch(void* const* d_in, const int* in_sizes, int n_in,
                              void* d_out, int out_size, void* d_ws, size_t ws_size,
                              hipStream_t stream)
{
    const float* x    = (const float*)d_in[0];
    const int*   ei   = (const int*)d_in[1];
    const float* embW = (const float*)d_in[2];
    const float* embb = (const float*)d_in[3];
    const float* W1   = (const float*)d_in[4];
    const float* b1   = (const float*)d_in[5];
    const float* W2   = (const float*)d_in[6];
    const float* b2   = (const float*)d_in[7];
    const float* gamma= (const float*)d_in[8];
    const float* beta = (const float*)d_in[9];

    int N = in_sizes[0] / NODE_IN;
    int E = in_sizes[1] / 2;
    int L = in_sizes[4] / (H * H2);
    const int* src = ei;
    const int* dst = ei + E;

    int numB = (N + 2047) / 2048;
    int T = (N + 15) / 16;           // 16-row tiles
    int nblk = (T + 15) / 16;        // 16 tiles (2 per wave) per block
    int R = nblk * 8;                // spart rows
    int Npad = nblk * 256;           // padded rows for hid

    char* w = (char*)d_ws;
    __bf16* zpb = (__bf16*)w;    w += (size_t)N * H * sizeof(__bf16);   // also h0
    w = align_up(w, 256);
    __bf16* zgb = (__bf16*)w;    w += (size_t)N * H * sizeof(__bf16);
    w = align_up(w, 256);
    __bf16* hid = (__bf16*)w;    w += (size_t)Npad * H2 * sizeof(__bf16);
    w = align_up(w, 256);
    float* spart = (float*)w;    w += (size_t)R * 256 * sizeof(float);
    float* statsAll = (float*)w; w += (size_t)L * 2 * H * sizeof(float);
    float* ss = (float*)w;       w += 2 * H * sizeof(float);
    int* deg = (int*)w;          w += (size_t)N * sizeof(int);
    int* offp = (int*)w;         w += (size_t)(N + 1) * sizeof(int);
    int* cursor = (int*)w;       w += (size_t)N * sizeof(int);
    int* bsum = (int*)w;         w += (size_t)numB * sizeof(int);
    int* srcl = (int*)w;         w += (size_t)E * sizeof(int);
    w = align_up(w, 256);
    char* Ws = w;                w += (size_t)L * 131072 + H * NODE_IN * 2;

    float* out = (float*)d_out;
    __bf16* h0 = zpb;            // alias: h0 dead after gather of layer 0

    // ---- once-per-launch prep ----
    int wtotal = 2 * L * H * H2 + H * NODE_IN;
    convert_weights_kernel<<<(wtotal + 255) / 256, 256, 0, stream>>>(W1, W2, embW, Ws, L);
    embed_kernel<<<(N + 127) / 128, 512, 0, stream>>>(
        x, Ws + (size_t)L * 131072, embb, h0, N);

    hipMemsetAsync(deg, 0, (size_t)N * sizeof(int), stream);
    hipMemsetAsync(statsAll, 0, (size_t)L * 2 * H * sizeof(float), stream);

    hist_kernel<<<(E + 255) / 256, 256, 0, stream>>>(dst, deg, E);
    scan_partial_kernel<<<numB, 256, 0, stream>>>(deg, bsum, N);
    scan_bsum_kernel<<<1, 256, 0, stream>>>(bsum, offp + N, numB);
    scan_apply_kernel<<<numB, 256, 0, stream>>>(deg, bsum, offp, cursor, N);
    fill_kernel<<<(E + 255) / 256, 256, 0, stream>>>(src, dst, cursor, srcl, E);

    int ggrid = (N * 16 + 255) / 256;
    int agrid = (int)(((size_t)N * (H / 8) + 255) / 256);

    for (int l = 0; l < L; ++l) {
        float* stats = statsAll + (size_t)l * 2 * H;
        const __bf16* hin = (l == 0) ? h0 : zpb;
        if (l == 0)
            gather_kernel<0><<<ggrid, 256, 0, stream>>>(hin, nullptr, offp, srcl, zgb, N);
        else
            gather_kernel<1><<<ggrid, 256, 0, stream>>>(hin, ss, offp, srcl, zgb, N);
        gemm1_kernel<<<nblk, 512, 0, stream>>>(
            zgb, hid, Ws + (size_t)l * 131072, b1 + (size_t)l * H2, N);
        gemm2_kernel<<<nblk, 512, 0, stream>>>(
            hid, zpb, Ws + (size_t)l * 131072 + 65536, b2 + (size_t)l * H, spart, N);
        reduce_stats_kernel<<<64, 256, 0, stream>>>(spart, stats, R);
        bn_finalize_kernel<<<1, H, 0, stream>>>(
            stats, gamma + (size_t)l * H, beta + (size_t)l * H, ss, N);
    }
    bn_apply_kernel<<<agrid, 256, 0, stream>>>(zpb, ss, out, N);
}

// Round 10
// 546.962 us; speedup vs baseline: 1.1854x; 1.1854x over previous
//
#include <hip/hip_runtime.h>

#define H 128
#define H2 256
#define NODE_IN 32
#define BN_EPS 1e-5f

typedef __bf16 bf16x8 __attribute__((ext_vector_type(8)));
typedef __bf16 bf16x4 __attribute__((ext_vector_type(4)));
typedef float f32x4 __attribute__((ext_vector_type(4)));

#define MFMA(a, b, c) __builtin_amdgcn_mfma_f32_16x16x32_bf16(a, b, c, 0, 0, 0)

// ---------------------------------------------------------------------------
// Weights -> bf16, transposed, XOR-swizzled GLOBAL layout (consumed linearly
// by global_load_lds so the LDS copy is swizzled; reads use chunk^(row&7)).
// W1 [L][128][256] -> per layer at l*131072       : row n(0..255) x 256B
// W2 [L][256][128] -> per layer at l*131072+65536 : row n(0..127) x 512B
// embW [32][128]   -> at L*131072: Wt_e[c][k], row c(0..127) x 64B (no swizzle)
__global__ __launch_bounds__(256) void convert_weights_kernel(
    const float* __restrict__ W1, const float* __restrict__ W2,
    const float* __restrict__ embW, char* __restrict__ Ws, int L)
{
    int idx = blockIdx.x * 256 + threadIdx.x;
    int per = H * H2;
    int total = L * per;
    if (idx < total) {
        int l = idx / per, r = idx % per;
        int k = r / H2, n = r % H2;          // W1[l][k][n]
        int c = k >> 3, e = k & 7;
        size_t off = (size_t)l * 131072 + n * 256 + (((c ^ (n & 7)) << 4)) + e * 2;
        *(__bf16*)(Ws + off) = (__bf16)W1[idx];
    } else if (idx < 2 * total) {
        int j = idx - total;
        int l = j / per, r = j % per;
        int k = r / H, n = r % H;            // W2[l][k][n]
        int c = k >> 3, e = k & 7;
        size_t off = (size_t)l * 131072 + 65536 + n * 512 + (((c ^ (n & 7)) << 4)) + e * 2;
        *(__bf16*)(Ws + off) = (__bf16)W2[j];
    } else if (idx < 2 * total + H * NODE_IN) {
        int j = idx - 2 * total;
        int k = j / H, c = j % H;            // embW[k][c]
        size_t off = (size_t)L * 131072 + c * 64 + k * 2;
        *(__bf16*)(Ws + off) = (__bf16)embW[j];
    }
}

// ---------------------------------------------------------------------------
// h0 = x @ emb_W + emb_b via MFMA (K=32 = one mfma_16x16x32).
// 8 waves x 16 rows; A = Wt_e frags (regs, from L2), B = x rows (fp32->bf16).
__global__ __launch_bounds__(512) void embed_kernel(
    const float* __restrict__ x, const char* __restrict__ Wse,
    const float* __restrict__ bias, __bf16* __restrict__ h, int N)
{
    int tid = threadIdx.x;
    int w = tid >> 6, lane = tid & 63;
    int l15 = lane & 15, kg = lane >> 4;

    bf16x8 aw[8];
#pragma unroll
    for (int nt = 0; nt < 8; ++nt)
        aw[nt] = *(const bf16x8*)(Wse + (nt * 16 + l15) * 64 + kg * 16);

    int r = (blockIdx.x * 8 + w) * 16 + l15;
    bool ok = (r < N);

    bf16x8 xb = {};
    if (ok) {
        float4 v0 = *(const float4*)&x[(size_t)r * NODE_IN + kg * 8];
        float4 v1 = *(const float4*)&x[(size_t)r * NODE_IN + kg * 8 + 4];
        xb[0] = (__bf16)v0.x; xb[1] = (__bf16)v0.y;
        xb[2] = (__bf16)v0.z; xb[3] = (__bf16)v0.w;
        xb[4] = (__bf16)v1.x; xb[5] = (__bf16)v1.y;
        xb[6] = (__bf16)v1.z; xb[7] = (__bf16)v1.w;
    }

    __bf16* hr = h + (size_t)r * H;
#pragma unroll
    for (int nt = 0; nt < 8; ++nt) {
        f32x4 acc = {0.f, 0.f, 0.f, 0.f};
        acc = MFMA(aw[nt], xb, acc);
        if (ok) {
            float4 bb = *(const float4*)&bias[nt * 16 + kg * 4];
            bf16x4 hv;
            hv[0] = (__bf16)(acc[0] + bb.x);
            hv[1] = (__bf16)(acc[1] + bb.y);
            hv[2] = (__bf16)(acc[2] + bb.z);
            hv[3] = (__bf16)(acc[3] + bb.w);
            *(bf16x4*)(hr + nt * 16 + kg * 4) = hv;
        }
    }
}

// ---------------------------------------------------------------------------
// CSR build
__global__ __launch_bounds__(256) void hist_kernel(
    const int* __restrict__ dst, int* __restrict__ deg, int E)
{
    int e = blockIdx.x * 256 + threadIdx.x;
    if (e < E) atomicAdd(&deg[dst[e]], 1);
}

__global__ __launch_bounds__(256) void scan_partial_kernel(
    const int* __restrict__ deg, int* __restrict__ bsum, int N)
{
    __shared__ int red[256];
    int b = blockIdx.x, t = threadIdx.x;
    int base = b * 2048 + t * 8;
    int s = 0;
#pragma unroll
    for (int i = 0; i < 8; ++i) { int idx = base + i; if (idx < N) s += deg[idx]; }
    red[t] = s;
    __syncthreads();
    for (int d = 128; d > 0; d >>= 1) {
        if (t < d) red[t] += red[t + d];
        __syncthreads();
    }
    if (t == 0) bsum[b] = red[0];
}

__global__ __launch_bounds__(256) void scan_bsum_kernel(
    int* __restrict__ bsum, int* __restrict__ total, int numB)
{
    __shared__ int ts[256];
    int t = threadIdx.x;
    int v = (t < numB) ? bsum[t] : 0;
    ts[t] = v;
    __syncthreads();
    for (int d = 1; d < 256; d <<= 1) {
        int u = (t >= d) ? ts[t - d] : 0;
        __syncthreads();
        ts[t] += u;
        __syncthreads();
    }
    if (t < numB) bsum[t] = ts[t] - v;
    if (t == 255) *total = ts[255];
}

__global__ __launch_bounds__(256) void scan_apply_kernel(
    const int* __restrict__ deg, const int* __restrict__ bsum,
    int* __restrict__ offp, int* __restrict__ cursor, int N)
{
    __shared__ int ts[256];
    int b = blockIdx.x, t = threadIdx.x;
    int base = b * 2048 + t * 8;
    int loc[8];
    int s = 0;
#pragma unroll
    for (int i = 0; i < 8; ++i) {
        int idx = base + i;
        loc[i] = (idx < N) ? deg[idx] : 0;
        s += loc[i];
    }
    ts[t] = s;
    __syncthreads();
    for (int d = 1; d < 256; d <<= 1) {
        int u = (t >= d) ? ts[t - d] : 0;
        __syncthreads();
        ts[t] += u;
        __syncthreads();
    }
    int run = bsum[b] + ts[t] - s;
#pragma unroll
    for (int i = 0; i < 8; ++i) {
        int idx = base + i;
        if (idx < N) { offp[idx] = run; cursor[idx] = run; }
        run += loc[i];
    }
}

__global__ __launch_bounds__(256) void fill_kernel(
    const int* __restrict__ src, const int* __restrict__ dst,
    int* __restrict__ cursor, int* __restrict__ srclist, int E)
{
    int e = blockIdx.x * 256 + threadIdx.x;
    if (e < E) {
        int pos = atomicAdd(&cursor[dst[e]], 1);
        srclist[pos] = src[e];
    }
}

// ---------------------------------------------------------------------------
// zg[v] = bf16( f(hin[v]) + sum_{nbr} f(hin[src]) ); f = BN?relu(v*sc+sh):v
// 16 lanes/node, bf16x8/lane; neighbor loop unrolled x4 for L3 latency hiding.
template <int BN>
__global__ __launch_bounds__(256) void gather_kernel(
    const __bf16* __restrict__ hin, const float* __restrict__ ss,
    const int* __restrict__ offp, const int* __restrict__ srclist,
    __bf16* __restrict__ zg, int N)
{
    int gid = blockIdx.x * 256 + threadIdx.x;
    int v = gid >> 4;
    if (v >= N) return;
    int c16 = gid & 15;
    float sc[8], sh[8];
    if (BN) {
#pragma unroll
        for (int j = 0; j < 8; ++j) { sc[j] = ss[c16 * 8 + j]; sh[j] = ss[H + c16 * 8 + j]; }
    }
    float acc[8];
    bf16x8 sv = *(const bf16x8*)(hin + (size_t)v * H + c16 * 8);
#pragma unroll
    for (int j = 0; j < 8; ++j) {
        float f = (float)sv[j];
        acc[j] = BN ? fmaxf(f * sc[j] + sh[j], 0.f) : f;
    }
    int i0 = offp[v], i1 = offp[v + 1];
    int i = i0;
    for (; i + 3 < i1; i += 4) {
        int s0 = srclist[i], s1 = srclist[i + 1];
        int s2 = srclist[i + 2], s3 = srclist[i + 3];
        bf16x8 u0 = *(const bf16x8*)(hin + (size_t)s0 * H + c16 * 8);
        bf16x8 u1 = *(const bf16x8*)(hin + (size_t)s1 * H + c16 * 8);
        bf16x8 u2 = *(const bf16x8*)(hin + (size_t)s2 * H + c16 * 8);
        bf16x8 u3 = *(const bf16x8*)(hin + (size_t)s3 * H + c16 * 8);
#pragma unroll
        for (int j = 0; j < 8; ++j) {
            float f0 = (float)u0[j], f1 = (float)u1[j];
            float f2 = (float)u2[j], f3 = (float)u3[j];
            if (BN) {
                f0 = fmaxf(f0 * sc[j] + sh[j], 0.f);
                f1 = fmaxf(f1 * sc[j] + sh[j], 0.f);
                f2 = fmaxf(f2 * sc[j] + sh[j], 0.f);
                f3 = fmaxf(f3 * sc[j] + sh[j], 0.f);
            }
            acc[j] += (f0 + f1) + (f2 + f3);
        }
    }
    for (; i < i1; ++i) {
        int s0 = srclist[i];
        bf16x8 u0 = *(const bf16x8*)(hin + (size_t)s0 * H + c16 * 8);
#pragma unroll
        for (int j = 0; j < 8; ++j) {
            float f0 = (float)u0[j];
            if (BN) f0 = fmaxf(f0 * sc[j] + sh[j], 0.f);
            acc[j] += f0;
        }
    }
    bf16x8 o;
#pragma unroll
    for (int j = 0; j < 8; ++j) o[j] = (__bf16)acc[j];
    *(bf16x8*)(zg + (size_t)v * H + c16 * 8) = o;
}

// ---------------------------------------------------------------------------
// GEMM1: hid = relu(zg @ W1 + b1). 8 waves/block; W1 (64KB, swizzled) in LDS;
// one barrier; each wave TWO independent 16-row tiles (stage amortized 2x).
// Swapped MFMA: A = W1 frag (LDS), B = zg rows. D lane -> node l15, 4 cols.
__global__ __launch_bounds__(512, 2) void gemm1_kernel(
    const __bf16* __restrict__ zg, __bf16* __restrict__ hid,
    const char* __restrict__ Ws1, const float* __restrict__ b1l, int N)
{
    __shared__ __align__(16) char lds[65536];
    int tid = threadIdx.x;
    int w = tid >> 6, lane = tid & 63;
    int l15 = lane & 15, kg = lane >> 4;

#pragma unroll
    for (int i = 0; i < 8; ++i) {
        const char* g = Ws1 + i * 8192 + tid * 16;
        char* l = lds + i * 8192 + w * 1024;   // wave-uniform base; HW adds lane*16
        __builtin_amdgcn_global_load_lds(
            (const __attribute__((address_space(1))) void*)g,
            (__attribute__((address_space(3))) void*)l, 16, 0, 0);
    }

    int tile0 = blockIdx.x * 16 + w * 2;
    int r0 = tile0 * 16 + l15;
    int r1 = r0 + 16;
    bool ok0 = (r0 < N), ok1 = (r1 < N);

    // tile-0 B fragments preloaded (overlaps weight staging)
    bf16x8 zb[4];
    {
        const __bf16* zr = zg + (size_t)r0 * H + kg * 8;
#pragma unroll
        for (int kk = 0; kk < 4; ++kk) {
            bf16x8 v = {};
            if (ok0) v = *(const bf16x8*)(zr + kk * 32);
            zb[kk] = v;
        }
    }

    __syncthreads();   // weights resident

    const int xsw = (l15 & 7) << 4;

#pragma unroll
    for (int s = 0; s < 2; ++s) {
        if (s == 1) {
            const __bf16* zr = zg + (size_t)r1 * H + kg * 8;
#pragma unroll
            for (int kk = 0; kk < 4; ++kk) {
                bf16x8 v = {};
                if (ok1) v = *(const bf16x8*)(zr + kk * 32);
                zb[kk] = v;
            }
        }
        int r = s ? r1 : r0;
        bool ok = s ? ok1 : ok0;
        __bf16* hr = hid + (size_t)r * H2;
#pragma unroll
        for (int nt = 0; nt < 16; ++nt) {
            f32x4 acc = {0.f, 0.f, 0.f, 0.f};
            const char* wrow = lds + (nt * 16 + l15) * 256;
#pragma unroll
            for (int kk = 0; kk < 4; ++kk) {
                bf16x8 aw = *(const bf16x8*)(wrow + (((kk * 4 + kg) << 4) ^ xsw));
                acc = MFMA(aw, zb[kk], acc);
            }
            if (ok) {
                float4 bb = *(const float4*)&b1l[nt * 16 + kg * 4];
                bf16x4 hv;
                hv[0] = (__bf16)fmaxf(acc[0] + bb.x, 0.f);
                hv[1] = (__bf16)fmaxf(acc[1] + bb.y, 0.f);
                hv[2] = (__bf16)fmaxf(acc[2] + bb.z, 0.f);
                hv[3] = (__bf16)fmaxf(acc[3] + bb.w, 0.f);
                *(bf16x4*)(hr + nt * 16 + kg * 4) = hv;
            }
        }
    }
}

// ---------------------------------------------------------------------------
// GEMM2: zp = hid @ W2 + b2 (pre-BN) + BN stats. Stats reduced per-nt2 via
// shfl + LDS atomics (no register arrays -> no spill). Block writes one
// spart row at the end.
__global__ __launch_bounds__(512, 2) void gemm2_kernel(
    const __bf16* __restrict__ hid, __bf16* __restrict__ zpb,
    const char* __restrict__ Ws2, const float* __restrict__ b2l,
    float* __restrict__ spart, int N)
{
    __shared__ __align__(16) char lds[65536];
    __shared__ float sstat[256];
    int tid = threadIdx.x;
    int w = tid >> 6, lane = tid & 63;
    int l15 = lane & 15, kg = lane >> 4;

#pragma unroll
    for (int i = 0; i < 8; ++i) {
        const char* g = Ws2 + i * 8192 + tid * 16;
        char* l = lds + i * 8192 + w * 1024;
        __builtin_amdgcn_global_load_lds(
            (const __attribute__((address_space(1))) void*)g,
            (__attribute__((address_space(3))) void*)l, 16, 0, 0);
    }
    if (tid < 256) sstat[tid] = 0.f;

    int tile0 = blockIdx.x * 16 + w * 2;
    int r0 = tile0 * 16 + l15;
    int r1 = r0 + 16;
    bool ok0 = (r0 < N), ok1 = (r1 < N);

    // tile-0 B fragments preloaded (overlaps weight staging)
    bf16x8 bd[8];
    {
        const __bf16* hr = hid + (size_t)r0 * H2 + kg * 8;
#pragma unroll
        for (int kk = 0; kk < 8; ++kk) {
            bf16x8 v = {};
            if (ok0) v = *(const bf16x8*)(hr + kk * 32);
            bd[kk] = v;
        }
    }

    __syncthreads();   // weights + sstat ready

    const int xsw = (l15 & 7) << 4;

#pragma unroll
    for (int s = 0; s < 2; ++s) {
        if (s == 1) {
            const __bf16* hr = hid + (size_t)r1 * H2 + kg * 8;
#pragma unroll
            for (int kk = 0; kk < 8; ++kk) {
                bf16x8 v = {};
                if (ok1) v = *(const bf16x8*)(hr + kk * 32);
                bd[kk] = v;
            }
        }
        int r = s ? r1 : r0;
        bool ok = s ? ok1 : ok0;
        __bf16* zr = zpb + (size_t)r * H;
#pragma unroll
        for (int nt2 = 0; nt2 < 8; ++nt2) {
            f32x4 acc = {0.f, 0.f, 0.f, 0.f};
            const char* wrow = lds + (nt2 * 16 + l15) * 512;
#pragma unroll
            for (int kk = 0; kk < 8; ++kk) {
                bf16x8 aw = *(const bf16x8*)(wrow + (((kk * 4 + kg) << 4) ^ xsw));
                acc = MFMA(aw, bd[kk], acc);
            }
            float4 bb = *(const float4*)&b2l[nt2 * 16 + kg * 4];
            float v0 = 0.f, v1 = 0.f, v2 = 0.f, v3 = 0.f;
            if (ok) {
                v0 = acc[0] + bb.x; v1 = acc[1] + bb.y;
                v2 = acc[2] + bb.z; v3 = acc[3] + bb.w;
                bf16x4 ov;
                ov[0] = (__bf16)v0; ov[1] = (__bf16)v1;
                ov[2] = (__bf16)v2; ov[3] = (__bf16)v3;
                *(bf16x4*)(zr + nt2 * 16 + kg * 4) = ov;
            }
            // immediate reduce over the 16 l15-lanes; LDS atomic accumulate
            float q0 = v0 * v0, q1 = v1 * v1, q2 = v2 * v2, q3 = v3 * v3;
            v0 += __shfl_xor(v0, 1, 64); q0 += __shfl_xor(q0, 1, 64);
            v0 += __shfl_xor(v0, 2, 64); q0 += __shfl_xor(q0, 2, 64);
            v0 += __shfl_xor(v0, 4, 64); q0 += __shfl_xor(q0, 4, 64);
            v0 += __shfl_xor(v0, 8, 64); q0 += __shfl_xor(q0, 8, 64);
            v1 += __shfl_xor(v1, 1, 64); q1 += __shfl_xor(q1, 1, 64);
            v1 += __shfl_xor(v1, 2, 64); q1 += __shfl_xor(q1, 2, 64);
            v1 += __shfl_xor(v1, 4, 64); q1 += __shfl_xor(q1, 4, 64);
            v1 += __shfl_xor(v1, 8, 64); q1 += __shfl_xor(q1, 8, 64);
            v2 += __shfl_xor(v2, 1, 64); q2 += __shfl_xor(q2, 1, 64);
            v2 += __shfl_xor(v2, 2, 64); q2 += __shfl_xor(q2, 2, 64);
            v2 += __shfl_xor(v2, 4, 64); q2 += __shfl_xor(q2, 4, 64);
            v2 += __shfl_xor(v2, 8, 64); q2 += __shfl_xor(q2, 8, 64);
            v3 += __shfl_xor(v3, 1, 64); q3 += __shfl_xor(q3, 1, 64);
            v3 += __shfl_xor(v3, 2, 64); q3 += __shfl_xor(q3, 2, 64);
            v3 += __shfl_xor(v3, 4, 64); q3 += __shfl_xor(q3, 4, 64);
            v3 += __shfl_xor(v3, 8, 64); q3 += __shfl_xor(q3, 8, 64);
            if (l15 == 0) {
                int c = nt2 * 16 + kg * 4;
                atomicAdd(&sstat[c + 0], v0);
                atomicAdd(&sstat[c + 1], v1);
                atomicAdd(&sstat[c + 2], v2);
                atomicAdd(&sstat[c + 3], v3);
                atomicAdd(&sstat[H + c + 0], q0);
                atomicAdd(&sstat[H + c + 1], q1);
                atomicAdd(&sstat[H + c + 2], q2);
                atomicAdd(&sstat[H + c + 3], q3);
            }
        }
    }

    __syncthreads();
    if (tid < 256) spart[(size_t)blockIdx.x * 256 + tid] = sstat[tid];
}

// ---------------------------------------------------------------------------
__global__ __launch_bounds__(256) void reduce_stats_kernel(
    const float* __restrict__ spart, float* __restrict__ stats, int R)
{
    int t = threadIdx.x;
    int b = blockIdx.x;
    int per = (R + gridDim.x - 1) / gridDim.x;
    int r0 = b * per, r1 = r0 + per;
    if (r1 > R) r1 = R;
    float s = 0.f;
    for (int r = r0; r < r1; ++r) s += spart[(size_t)r * 256 + t];
    atomicAdd(&stats[t], s);
}

// ---------------------------------------------------------------------------
__global__ void bn_finalize_kernel(const float* __restrict__ stats,
                                   const float* __restrict__ gamma,
                                   const float* __restrict__ beta,
                                   float* __restrict__ ss, int N)
{
    int j = threadIdx.x;
    float invN = 1.0f / (float)N;
    float mean = stats[j] * invN;
    float var = stats[H + j] * invN - mean * mean;
    float sc = gamma[j] * rsqrtf(var + BN_EPS);
    ss[j] = sc;
    ss[H + j] = beta[j] - mean * sc;
}

// ---------------------------------------------------------------------------
// out = relu(zpb*scale + shift), bf16 -> fp32
__global__ __launch_bounds__(256) void bn_apply_kernel(
    const __bf16* __restrict__ zpb, const float* __restrict__ ss,
    float* __restrict__ out, int N)
{
    size_t i = (size_t)blockIdx.x * 256 + threadIdx.x;   // 8-elem units
    size_t total = (size_t)N * (H / 8);
    if (i >= total) return;
    int c8 = (int)(i & (H / 8 - 1));
    bf16x8 v = *(const bf16x8*)(zpb + i * 8);
    float4 o0, o1;
    const float* scp = &ss[c8 * 8];
    const float* shp = &ss[H + c8 * 8];
    o0.x = fmaxf((float)v[0] * scp[0] + shp[0], 0.f);
    o0.y = fmaxf((float)v[1] * scp[1] + shp[1], 0.f);
    o0.z = fmaxf((float)v[2] * scp[2] + shp[2], 0.f);
    o0.w = fmaxf((float)v[3] * scp[3] + shp[3], 0.f);
    o1.x = fmaxf((float)v[4] * scp[4] + shp[4], 0.f);
    o1.y = fmaxf((float)v[5] * scp[5] + shp[5], 0.f);
    o1.z = fmaxf((float)v[6] * scp[6] + shp[6], 0.f);
    o1.w = fmaxf((float)v[7] * scp[7] + shp[7], 0.f);
    ((float4*)out)[i * 2] = o0;
    ((float4*)out)[i * 2 + 1] = o1;
}

// ---------------------------------------------------------------------------
static inline char* align_up(char* p, size_t a) {
    return (char*)(((uintptr_t)p + a - 1) & ~(uintptr_t)(a - 1));
}

extern "C" void kernel_launch(void* const* d_in, const int* in_sizes, int n_in,
                              void* d_out, int out_size, void* d_ws, size_t ws_size,
                              hipStream_t stream)
{
    const float* x    = (const float*)d_in[0];
    const int*   ei   = (const int*)d_in[1];
    const float* embW = (const float*)d_in[2];
    const float* embb = (const float*)d_in[3];
    const float* W1   = (const float*)d_in[4];
    const float* b1   = (const float*)d_in[5];
    const float* W2   = (const float*)d_in[6];
    const float* b2   = (const float*)d_in[7];
    const float* gamma= (const float*)d_in[8];
    const float* beta = (const float*)d_in[9];

    int N = in_sizes[0] / NODE_IN;
    int E = in_sizes[1] / 2;
    int L = in_sizes[4] / (H * H2);
    const int* src = ei;
    const int* dst = ei + E;

    int numB = (N + 2047) / 2048;
    int T = (N + 15) / 16;           // 16-row tiles
    int nblk = (T + 15) / 16;        // 16 tiles (2 per wave) per block
    int R = nblk;                    // spart rows (one per block)
    int Npad = nblk * 256;           // padded rows for hid

    char* w = (char*)d_ws;
    __bf16* zpb = (__bf16*)w;    w += (size_t)N * H * sizeof(__bf16);   // also h0
    w = align_up(w, 256);
    __bf16* zgb = (__bf16*)w;    w += (size_t)N * H * sizeof(__bf16);
    w = align_up(w, 256);
    __bf16* hid = (__bf16*)w;    w += (size_t)Npad * H2 * sizeof(__bf16);
    w = align_up(w, 256);
    float* spart = (float*)w;    w += (size_t)R * 256 * sizeof(float);
    float* statsAll = (float*)w; w += (size_t)L * 2 * H * sizeof(float);
    float* ss = (float*)w;       w += 2 * H * sizeof(float);
    int* deg = (int*)w;          w += (size_t)N * sizeof(int);
    int* offp = (int*)w;         w += (size_t)(N + 1) * sizeof(int);
    int* cursor = (int*)w;       w += (size_t)N * sizeof(int);
    int* bsum = (int*)w;         w += (size_t)numB * sizeof(int);
    int* srcl = (int*)w;         w += (size_t)E * sizeof(int);
    w = align_up(w, 256);
    char* Ws = w;                w += (size_t)L * 131072 + H * NODE_IN * 2;

    float* out = (float*)d_out;
    __bf16* h0 = zpb;            // alias: h0 dead after gather of layer 0

    // ---- once-per-launch prep ----
    int wtotal = 2 * L * H * H2 + H * NODE_IN;
    convert_weights_kernel<<<(wtotal + 255) / 256, 256, 0, stream>>>(W1, W2, embW, Ws, L);
    embed_kernel<<<(N + 127) / 128, 512, 0, stream>>>(
        x, Ws + (size_t)L * 131072, embb, h0, N);

    hipMemsetAsync(deg, 0, (size_t)N * sizeof(int), stream);
    hipMemsetAsync(statsAll, 0, (size_t)L * 2 * H * sizeof(float), stream);

    hist_kernel<<<(E + 255) / 256, 256, 0, stream>>>(dst, deg, E);
    scan_partial_kernel<<<numB, 256, 0, stream>>>(deg, bsum, N);
    scan_bsum_kernel<<<1, 256, 0, stream>>>(bsum, offp + N, numB);
    scan_apply_kernel<<<numB, 256, 0, stream>>>(deg, bsum, offp, cursor, N);
    fill_kernel<<<(E + 255) / 256, 256, 0, stream>>>(src, dst, cursor, srcl, E);

    int ggrid = (N * 16 + 255) / 256;
    int agrid = (int)(((size_t)N * (H / 8) + 255) / 256);

    for (int l = 0; l < L; ++l) {
        float* stats = statsAll + (size_t)l * 2 * H;
        const __bf16* hin = (l == 0) ? h0 : zpb;
        if (l == 0)
            gather_kernel<0><<<ggrid, 256, 0, stream>>>(hin, nullptr, offp, srcl, zgb, N);
        else
            gather_kernel<1><<<ggrid, 256, 0, stream>>>(hin, ss, offp, srcl, zgb, N);
        gemm1_kernel<<<nblk, 512, 0, stream>>>(
            zgb, hid, Ws + (size_t)l * 131072, b1 + (size_t)l * H2, N);
        gemm2_kernel<<<nblk, 512, 0, stream>>>(
            hid, zpb, Ws + (size_t)l * 131072 + 65536, b2 + (size_t)l * H, spart, N);
        reduce_stats_kernel<<<64, 256, 0, stream>>>(spart, stats, R);
        bn_finalize_kernel<<<1, H, 0, stream>>>(
            stats, gamma + (size_t)l * H, beta + (size_t)l * H, ss, N);
    }
    bn_apply_kernel<<<agrid, 256, 0, stream>>>(zpb, ss, out, N);
}